// Round 3
// baseline (521.725 us; speedup 1.0000x reference)
//
#include <hip/hip_runtime.h>
#include <math.h>

#define KDIM 128
#define TLEN 512
#define BATCH 16
#define CH_L 16
#define NCH 32           // chunks per batch (phase 3)
#define NMAT 31          // chunk matrices (phase 1/2): chunk c covers t in [16c+1, 16c+16]

typedef _Float16 half8 __attribute__((ext_vector_type(8)));
typedef float floatx4 __attribute__((ext_vector_type(4)));

// ---------------- ws layout (bytes) ----------------
#define WS_PST   0
#define WS_EBL   16252928
#define WS_SLOG  16285696
#define WS_AENT  16287680
#define WS_MT    16549824
#define WS_NEED  16549828

// A-operand LDS/ws layout for mfma_f32_16x16x32_f16 (fragment-contiguous):
//   Aidx(i,k) = (((i>>4)*16 + (k>>3))*16 + (i&15))*8 + (k&7)
// B-operand:  Bidx(k,n) = (((n>>4)*16 + (k>>3))*16 + (n&15))*8 + (k&7)
// Frag maps (guide §3): A: lane holds A[m=lane&15][k=quad*8+j], quad=lane>>4.
// C/D: col=lane&15, row=quad*4+reg.  (Validated empirically in R2: the only
// error was the S log-scale overcount, a clean c*15*mT ramp.)

// ================= prep: Estore = exp(trans - mT), B-layout, f16 =================
__global__ __launch_bounds__(256) void crf_prepE(const float* __restrict__ trans,
                                                 _Float16* __restrict__ Ebl,
                                                 float* __restrict__ mTout)
{
    const int tid = threadIdx.x;
    __shared__ float slot[4];
    float mt = -INFINITY;
    for (int s = 0; s < 64; ++s) mt = fmaxf(mt, trans[tid + s * 256]);
    #pragma unroll
    for (int o = 32; o; o >>= 1) mt = fmaxf(mt, __shfl_xor(mt, o));
    if ((tid & 63) == 0) slot[tid >> 6] = mt;
    __syncthreads();
    const float mT = fmaxf(fmaxf(slot[0], slot[1]), fmaxf(slot[2], slot[3]));
    for (int s = 0; s < 64; ++s) {
        int e = tid + s * 256;
        int k = e >> 7, n = e & 127;
        Ebl[(((n >> 4) * 16 + (k >> 3)) * 16 + (n & 15)) * 8 + (k & 7)] =
            (_Float16)__expf(trans[e] - mT);
    }
    if (tid == 0) mTout[0] = mT;
}

// ================= phase 1: chunk products via MFMA =================
__global__ __launch_bounds__(256, 2) void crf_chunkmat(
    const float* __restrict__ trans, const float* __restrict__ em,
    const _Float16* __restrict__ Ebl, const float* __restrict__ mTws,
    _Float16* __restrict__ Pst, float* __restrict__ Sout)
{
    const int c = blockIdx.x;     // 0..NMAT-1
    const int b = blockIdx.y;
    const int tid = threadIdx.x;
    const int w = tid >> 6, lane = tid & 63;
    const int quad = lane >> 4, lm = lane & 15;

    __shared__ __align__(16) _Float16 Alds[16384];   // 32 KB, A-frag layout
    __shared__ float gbuf[2][KDIM];
    __shared__ float slotV[4];
    __shared__ float slotE[2][2];

    const float mT = mTws[0];
    const int t0 = c * CH_L + 1;              // chunk covers M_t, t = t0 .. t0+15
    const float* emb = em + (size_t)b * TLEN * KDIM;

    // --- em maxes + g for t0 and t0+1 ---
    float ev0 = 0.f, ev1 = 0.f;
    if (tid < KDIM) {
        ev0 = emb[t0 * KDIM + tid];
        ev1 = emb[(t0 + 1) * KDIM + tid];
    }
    float m0 = (tid < KDIM) ? ev0 : -INFINITY;
    #pragma unroll
    for (int o = 32; o; o >>= 1) m0 = fmaxf(m0, __shfl_xor(m0, o));
    float m1 = (tid < KDIM) ? ev1 : -INFINITY;
    #pragma unroll
    for (int o = 32; o; o >>= 1) m1 = fmaxf(m1, __shfl_xor(m1, o));
    if (lane == 0 && w < 2) { slotE[0][w] = m0; slotE[1][w] = m1; }
    __syncthreads();
    const float mE0 = fmaxf(slotE[0][0], slotE[0][1]);
    const float mE1 = fmaxf(slotE[1][0], slotE[1][1]);
    if (tid < KDIM) {
        gbuf[0][tid] = __expf(ev0 - mE0);
        gbuf[1][tid] = __expf(ev1 - mE1);
    }
    __syncthreads();

    // --- A init: P = M_t0 = exp(trans - mT) * g0[j], into A-layout ---
    for (int s = 0; s < 64; ++s) {
        int e = tid + s * 256;
        int i = e >> 7, j = e & 127;
        float va = __expf(trans[e] - mT) * gbuf[0][j];
        Alds[(((i >> 4) * 16 + (j >> 3)) * 16 + (i & 15)) * 8 + (j & 7)] = (_Float16)va;
    }
    __syncthreads();

    // Log-scale accumulator: covers M_t0 (mT + mE0), pre-adds mE1; each loop
    // iteration it adds mT + log(rr) for M_{t0+it} and mE for the following step.
    // (R2 bug: init had 16*mT -> overcounted 15*mT per chunk.)
    float S = mT + mE0 + mE1;   // only thread 0's copy matters
    floatx4 acc[2][8];
    const int tr0 = 2 * w, tr1 = 2 * w + 1;

    for (int it = 1; it < 16; ++it) {
        const int t = t0 + it;
        const bool hasnext = (it < 15);

        // prefetch em[t+1]
        float evn = 0.f;
        if (tid < KDIM && hasnext) evn = emb[(t + 1) * KDIM + tid];

        #pragma unroll
        for (int r = 0; r < 2; ++r)
            #pragma unroll
            for (int tj = 0; tj < 8; ++tj)
                acc[r][tj] = (floatx4){0.f, 0.f, 0.f, 0.f};

        // ---- C = P * E : A from LDS, B from global (L2-hot) ----
        #pragma unroll
        for (int ks = 0; ks < 4; ++ks) {
            half8 a0 = *(const half8*)&Alds[((tr0 * 16 + ks * 4 + quad) * 16 + lm) * 8];
            half8 a1 = *(const half8*)&Alds[((tr1 * 16 + ks * 4 + quad) * 16 + lm) * 8];
            #pragma unroll
            for (int tj = 0; tj < 8; ++tj) {
                half8 bb = *(const half8*)&Ebl[((tj * 16 + ks * 4 + quad) * 16 + lm) * 8];
                acc[0][tj] = __builtin_amdgcn_mfma_f32_16x16x32_f16(a0, bb, acc[0][tj], 0, 0, 0);
                acc[1][tj] = __builtin_amdgcn_mfma_f32_16x16x32_f16(a1, bb, acc[1][tj], 0, 0, 0);
            }
        }

        // next-step em max (off critical path)
        float mn = (tid < KDIM && hasnext) ? evn : -INFINITY;
        #pragma unroll
        for (int o = 32; o; o >>= 1) mn = fmaxf(mn, __shfl_xor(mn, o));
        if (lane == 0 && w < 2) slotE[it & 1][w] = mn;

        // local max of col-scaled C
        const float* gc = gbuf[it & 1];
        float lmax = 0.f;
        #pragma unroll
        for (int tj = 0; tj < 8; ++tj) {
            const float gcol = gc[tj * 16 + lm];
            #pragma unroll
            for (int r = 0; r < 2; ++r) {
                floatx4 v = acc[r][tj];
                float m4 = fmaxf(fmaxf(v.x, v.y), fmaxf(v.z, v.w));
                lmax = fmaxf(lmax, gcol * m4);
            }
        }
        #pragma unroll
        for (int o = 32; o; o >>= 1) lmax = fmaxf(lmax, __shfl_xor(lmax, o));
        if (lane == 0) slotV[w] = lmax;
        __syncthreads();                                   // barrier 1

        const float rr = fmaxf(fmaxf(slotV[0], slotV[1]), fmaxf(slotV[2], slotV[3]));
        const float rinv = 1.0f / rr;
        if (tid < KDIM && hasnext) {
            const float mEn = fmaxf(slotE[it & 1][0], slotE[it & 1][1]);
            gbuf[(it + 1) & 1][tid] = __expf(evn - mEn);
            if (tid == 0) S += mEn;
        }
        if (tid == 0) S += mT + __logf(rr);

        // write normalized P back to A-layout
        #pragma unroll
        for (int tj = 0; tj < 8; ++tj) {
            const float gs = gc[tj * 16 + lm] * rinv;
            const int j_ = tj * 16 + lm;
            const int jhi = (j_ >> 3), jlo = (j_ & 7);
            #pragma unroll
            for (int r = 0; r < 2; ++r) {
                const int ti = 2 * w + r;
                #pragma unroll
                for (int q = 0; q < 4; ++q) {
                    float v = acc[r][tj][q] * gs;
                    Alds[((ti * 16 + jhi) * 16 + (quad * 4 + q)) * 8 + jlo] = (_Float16)v;
                }
            }
        }
        __syncthreads();                                   // barrier 2
    }

    // --- write P (row-major f16) + S ---
    _Float16* Pc = Pst + ((size_t)(b * NMAT + c)) * 16384;
    for (int s = 0; s < 8; ++s) {
        int e8 = tid + s * 256;                  // 0..2047
        int i_ = e8 >> 4, jg = e8 & 15;
        half8 v = *(const half8*)&Alds[(((i_ >> 4) * 16 + jg) * 16 + (i_ & 15)) * 8];
        *(half8*)&Pc[i_ * 128 + jg * 8] = v;
    }
    if (tid == 0) Sout[b * NMAT + c] = S;
}

// ================= phase 2: sequential scan over chunk matrices =================
__global__ __launch_bounds__(512, 1) void crf_scan(
    const float* __restrict__ em, const _Float16* __restrict__ Pst,
    const float* __restrict__ S, float* __restrict__ aEnter)
{
    const int b = blockIdx.x;
    const int tid = threadIdx.x;
    const int j = tid & 127, qh = tid >> 7;
    __shared__ float p_lds[KDIM];
    __shared__ float part[4][KDIM];
    __shared__ float slot[2];

    float* aeb = aEnter + (size_t)b * NCH * KDIM;
    float a = 0.f;
    if (qh == 0) {
        a = em[(size_t)b * TLEN * KDIM + j];
        aeb[j] = a;
    }
    for (int c = 0; c < NMAT; ++c) {
        float v = (qh == 0) ? a : -INFINITY;
        #pragma unroll
        for (int o = 32; o; o >>= 1) v = fmaxf(v, __shfl_xor(v, o));
        if ((tid & 63) == 0 && qh == 0) slot[tid >> 6] = v;
        __syncthreads();
        const float mv = fmaxf(slot[0], slot[1]);
        if (qh == 0) p_lds[j] = __expf(a - mv);
        __syncthreads();

        const _Float16* Pc = Pst + ((size_t)(b * NMAT + c)) * 16384;
        float acc = 0.f;
        #pragma unroll 8
        for (int kk = 0; kk < 32; ++kk) {
            const int k = qh * 32 + kk;
            acc = fmaf(p_lds[k], (float)Pc[k * 128 + j], acc);
        }
        part[qh][j] = acc;
        __syncthreads();
        if (qh == 0) {
            float q = (part[0][j] + part[1][j]) + (part[2][j] + part[3][j]);
            a = mv + S[b * NMAT + c] + __logf(q);
            aeb[(c + 1) * KDIM + j] = a;
        }
        __syncthreads();
    }
}

// ================= phase 3: fp32 replay within chunks + logZ =================
__global__ __launch_bounds__(256, 2) void crf_replay(
    const float* __restrict__ trans, const float* __restrict__ em,
    const int* __restrict__ seq_lens, const float* __restrict__ aEnter,
    float* __restrict__ alpha, float* __restrict__ logZ)
{
    const int c = blockIdx.x, b = blockIdx.y;
    const int tid = threadIdx.x;
    const int j = tid & 127, h = tid >> 7;

    __shared__ __align__(16) float p_lds[2][KDIM];
    __shared__ float part[2][KDIM];
    __shared__ float mslot[2][2];
    __shared__ float red[2];

    float Ereg[64];
    #pragma unroll
    for (int k = 0; k < 64; ++k) Ereg[k] = __expf(trans[(h * 64 + k) * KDIM + j]);

    const int len = seq_lens[b];
    const float* emb = em + (size_t)b * TLEN * KDIM;
    float* outb = alpha + (size_t)b * TLEN * KDIM;

    float a = 0.f, last_a = 0.f;
    if (h == 0) a = aEnter[((size_t)b * NCH + c) * KDIM + j];
    if (c == 0 && h == 0) {
        outb[j] = a;
        if (len == 1) last_a = a;
    }
    // initial m = max(aEnter)
    {
        float v = (h == 0) ? a : -INFINITY;
        #pragma unroll
        for (int o = 32; o; o >>= 1) v = fmaxf(v, __shfl_xor(v, o));
        if ((tid & 63) == 0 && h == 0) mslot[0][tid >> 6] = v;
    }
    __syncthreads();
    float m = fmaxf(mslot[0][0], mslot[0][1]);

    const int t_begin = c * CH_L + 1;
    const int t_end = (c == NCH - 1) ? (TLEN - 1) : (c * CH_L + CH_L);

    for (int t = t_begin; t <= t_end; ++t) {
        const int par = t & 1;
        float em_t = 0.f;
        if (h == 0) {
            em_t = emb[t * KDIM + j];
            p_lds[par][j] = __expf(a - m);
            float v = a;
            #pragma unroll
            for (int o = 32; o; o >>= 1) v = fmaxf(v, __shfl_xor(v, o));
            if ((tid & 63) == 0) mslot[par][tid >> 6] = v;
        }
        __syncthreads();                                   // barrier 1
        float acc0 = 0.f, acc1 = 0.f, acc2 = 0.f, acc3 = 0.f;
        const float4* p4 = (const float4*)&p_lds[par][h * 64];
        #pragma unroll
        for (int k4 = 0; k4 < 16; ++k4) {
            float4 pv = p4[k4];
            acc0 = fmaf(pv.x, Ereg[4 * k4 + 0], acc0);
            acc1 = fmaf(pv.y, Ereg[4 * k4 + 1], acc1);
            acc2 = fmaf(pv.z, Ereg[4 * k4 + 2], acc2);
            acc3 = fmaf(pv.w, Ereg[4 * k4 + 3], acc3);
        }
        if (h) part[par][j] = (acc0 + acc1) + (acc2 + acc3);
        __syncthreads();                                   // barrier 2
        if (h == 0) {
            const float q = ((acc0 + acc1) + (acc2 + acc3)) + part[par][j];
            a = em_t + m + __logf(q);
            outb[t * KDIM + j] = a;
            if (t == len - 1) last_a = a;
            m = fmaxf(mslot[par][0], mslot[par][1]);
        }
    }

    // logZ: block owning position len-1
    const bool blockowns = (len == 1) ? (c == 0) : (((len - 2) >> 4) == c);
    __syncthreads();
    if (blockowns) {
        float v = (h == 0) ? last_a : -INFINITY;
        #pragma unroll
        for (int o = 32; o; o >>= 1) v = fmaxf(v, __shfl_xor(v, o));
        if ((tid & 63) == 0 && h == 0) mslot[0][tid >> 6] = v;
        __syncthreads();
        const float m2 = fmaxf(mslot[0][0], mslot[0][1]);
        float e = (h == 0) ? __expf(last_a - m2) : 0.f;
        #pragma unroll
        for (int o = 32; o; o >>= 1) e += __shfl_xor(e, o);
        if ((tid & 63) == 0 && h == 0) red[tid >> 6] = e;
        __syncthreads();
        if (tid == 0) logZ[b] = m2 + __logf(red[0] + red[1]);
    }
}

// ================= fallback (proven R1 kernel) for small ws =================
__global__ __launch_bounds__(256) void crf_forward_fallback(
    const float* __restrict__ trans, const float* __restrict__ em,
    const int* __restrict__ seq_lens, float* __restrict__ alpha_out,
    float* __restrict__ logZ_out)
{
    const int b = blockIdx.x;
    const int tid = threadIdx.x;
    const int j = tid & (KDIM - 1);
    const int h = tid >> 7;

    __shared__ __align__(16) float p_lds[KDIM];
    __shared__ float part[KDIM];
    __shared__ float red[8];

    float Ereg[64];
    #pragma unroll
    for (int k = 0; k < 64; ++k) Ereg[k] = __expf(trans[(h * 64 + k) * KDIM + j]);

    const int len = seq_lens[b];
    const float* emb = em + (size_t)b * TLEN * KDIM;
    float* outb = alpha_out + (size_t)b * TLEN * KDIM;

    float a = 0.f, last_a = 0.f;
    if (h == 0) {
        a = emb[j];
        outb[j] = a;
        if (len == 1) last_a = a;
    }
    for (int t = 1; t < TLEN; ++t) {
        {
            float v = (h == 0) ? a : -INFINITY;
            #pragma unroll
            for (int o = 32; o >= 1; o >>= 1) v = fmaxf(v, __shfl_xor(v, o));
            if ((tid & 63) == 0) red[tid >> 6] = v;
        }
        __syncthreads();
        const float m = fmaxf(red[0], red[1]);
        if (h == 0) p_lds[j] = __expf(a - m);
        __syncthreads();
        float em_t = 0.f;
        if (h == 0) em_t = emb[t * KDIM + j];
        float acc0 = 0.f, acc1 = 0.f, acc2 = 0.f, acc3 = 0.f;
        const float4* p4 = (const float4*)(p_lds + h * 64);
        #pragma unroll
        for (int k4 = 0; k4 < 16; ++k4) {
            float4 pv = p4[k4];
            acc0 = fmaf(pv.x, Ereg[4 * k4 + 0], acc0);
            acc1 = fmaf(pv.y, Ereg[4 * k4 + 1], acc1);
            acc2 = fmaf(pv.z, Ereg[4 * k4 + 2], acc2);
            acc3 = fmaf(pv.w, Ereg[4 * k4 + 3], acc3);
        }
        const float acc = (acc0 + acc1) + (acc2 + acc3);
        if (h == 1) part[j] = acc;
        __syncthreads();
        if (h == 0) {
            const float q = acc + part[j];
            a = em_t + m + __logf(q);
            outb[t * KDIM + j] = a;
            if (t == len - 1) last_a = a;
        }
    }
    {
        float v = (h == 0) ? last_a : -INFINITY;
        #pragma unroll
        for (int o = 32; o >= 1; o >>= 1) v = fmaxf(v, __shfl_xor(v, o));
        if ((tid & 63) == 0) red[tid >> 6] = v;
    }
    __syncthreads();
    const float m2 = fmaxf(red[0], red[1]);
    float e = (h == 0) ? __expf(last_a - m2) : 0.f;
    #pragma unroll
    for (int o = 32; o >= 1; o >>= 1) e += __shfl_xor(e, o);
    if ((tid & 63) == 0) red[4 + (tid >> 6)] = e;
    __syncthreads();
    if (tid == 0) logZ_out[b] = m2 + logf(red[4] + red[5]);
}

extern "C" void kernel_launch(void* const* d_in, const int* in_sizes, int n_in,
                              void* d_out, int out_size, void* d_ws, size_t ws_size,
                              hipStream_t stream) {
    const float* trans    = (const float*)d_in[0];   // K*K
    const float* em       = (const float*)d_in[1];   // B*T*K
    const int*   seq_lens = (const int*)d_in[2];     // B

    float* alpha_out = (float*)d_out;                            // B*T*K
    float* logZ_out  = alpha_out + (size_t)BATCH * TLEN * KDIM;  // B

    if (ws_size < (size_t)WS_NEED) {
        crf_forward_fallback<<<BATCH, 256, 0, stream>>>(trans, em, seq_lens,
                                                        alpha_out, logZ_out);
        return;
    }

    char* ws = (char*)d_ws;
    _Float16* Pst  = (_Float16*)(ws + WS_PST);
    _Float16* Ebl  = (_Float16*)(ws + WS_EBL);
    float*    Slog = (float*)(ws + WS_SLOG);
    float*    aEnt = (float*)(ws + WS_AENT);
    float*    mTws = (float*)(ws + WS_MT);

    crf_prepE<<<1, 256, 0, stream>>>(trans, Ebl, mTws);
    crf_chunkmat<<<dim3(NMAT, BATCH), 256, 0, stream>>>(trans, em, Ebl, mTws, Pst, Slog);
    crf_scan<<<BATCH, 512, 0, stream>>>(em, Pst, Slog, aEnt);
    crf_replay<<<dim3(NCH, BATCH), 256, 0, stream>>>(trans, em, seq_lens, aEnt,
                                                     alpha_out, logZ_out);
}

// Round 4
// 272.438 us; speedup vs baseline: 1.9150x; 1.9150x over previous
//
#include <hip/hip_runtime.h>
#include <math.h>

#define KDIM 128
#define TLEN 512
#define BATCH 16
#define CH_L 16
#define NCH 32           // chunks per batch (phase 3)
#define NMAT 31          // chunk matrices (phase 1/2): chunk c covers t in [16c+1, 16c+16]

typedef _Float16 half8 __attribute__((ext_vector_type(8)));
typedef float floatx4 __attribute__((ext_vector_type(4)));

// ---------------- ws layout (bytes) ----------------
#define WS_PST   0
#define WS_EBL   16252928
#define WS_SLOG  16285696
#define WS_AENT  16287680
#define WS_MT    16549824
#define WS_NEED  16549828

// A-operand LDS/ws layout for mfma_f32_16x16x32_f16 (fragment-contiguous):
//   Aidx(i,k) = (((i>>4)*16 + (k>>3))*16 + (i&15))*8 + (k&7)
// B-operand:  Bidx(k,n) = (((n>>4)*16 + (k>>3))*16 + (n&15))*8 + (k&7)
// Frag maps (guide §3): A: lane holds A[m=lane&15][k=quad*8+j], quad=lane>>4.
// C/D: col=lane&15, row=quad*4+reg.  (Validated empirically in R2/R3.)

// ================= prep: Estore = exp(trans - mT), B-layout, f16 =================
__global__ __launch_bounds__(256) void crf_prepE(const float* __restrict__ trans,
                                                 _Float16* __restrict__ Ebl,
                                                 float* __restrict__ mTout)
{
    const int tid = threadIdx.x;
    __shared__ float slot[4];
    float mt = -INFINITY;
    for (int s = 0; s < 64; ++s) mt = fmaxf(mt, trans[tid + s * 256]);
    #pragma unroll
    for (int o = 32; o; o >>= 1) mt = fmaxf(mt, __shfl_xor(mt, o));
    if ((tid & 63) == 0) slot[tid >> 6] = mt;
    __syncthreads();
    const float mT = fmaxf(fmaxf(slot[0], slot[1]), fmaxf(slot[2], slot[3]));
    for (int s = 0; s < 64; ++s) {
        int e = tid + s * 256;
        int k = e >> 7, n = e & 127;
        Ebl[(((n >> 4) * 16 + (k >> 3)) * 16 + (n & 15)) * 8 + (k & 7)] =
            (_Float16)__expf(trans[e] - mT);
    }
    if (tid == 0) mTout[0] = mT;
}

// ================= phase 1: chunk products via MFMA =================
__global__ __launch_bounds__(256, 2) void crf_chunkmat(
    const float* __restrict__ trans, const float* __restrict__ em,
    const _Float16* __restrict__ Ebl, const float* __restrict__ mTws,
    _Float16* __restrict__ Pst, float* __restrict__ Sout)
{
    const int c = blockIdx.x;     // 0..NMAT-1
    const int b = blockIdx.y;
    const int tid = threadIdx.x;
    const int w = tid >> 6, lane = tid & 63;
    const int quad = lane >> 4, lm = lane & 15;

    __shared__ __align__(16) _Float16 Alds[16384];   // 32 KB, A-frag layout
    __shared__ float gbuf[2][KDIM];
    __shared__ float slotV[4];
    __shared__ float slotE[2][2];

    const float mT = mTws[0];
    const int t0 = c * CH_L + 1;              // chunk covers M_t, t = t0 .. t0+15
    const float* emb = em + (size_t)b * TLEN * KDIM;

    // --- em maxes + g for t0 and t0+1 ---
    float ev0 = 0.f, ev1 = 0.f;
    if (tid < KDIM) {
        ev0 = emb[t0 * KDIM + tid];
        ev1 = emb[(t0 + 1) * KDIM + tid];
    }
    float m0 = (tid < KDIM) ? ev0 : -INFINITY;
    #pragma unroll
    for (int o = 32; o; o >>= 1) m0 = fmaxf(m0, __shfl_xor(m0, o));
    float m1 = (tid < KDIM) ? ev1 : -INFINITY;
    #pragma unroll
    for (int o = 32; o; o >>= 1) m1 = fmaxf(m1, __shfl_xor(m1, o));
    if (lane == 0 && w < 2) { slotE[0][w] = m0; slotE[1][w] = m1; }
    __syncthreads();
    const float mE0 = fmaxf(slotE[0][0], slotE[0][1]);
    const float mE1 = fmaxf(slotE[1][0], slotE[1][1]);
    if (tid < KDIM) {
        gbuf[0][tid] = __expf(ev0 - mE0);
        gbuf[1][tid] = __expf(ev1 - mE1);
    }
    __syncthreads();

    // --- A init: P = M_t0 = exp(trans - mT) * g0[j], into A-layout ---
    for (int s = 0; s < 64; ++s) {
        int e = tid + s * 256;
        int i = e >> 7, j = e & 127;
        float va = __expf(trans[e] - mT) * gbuf[0][j];
        Alds[(((i >> 4) * 16 + (j >> 3)) * 16 + (i & 15)) * 8 + (j & 7)] = (_Float16)va;
    }
    __syncthreads();

    float S = mT + mE0 + mE1;   // only thread 0's copy matters
    floatx4 acc[2][8];
    const int tr0 = 2 * w, tr1 = 2 * w + 1;

    for (int it = 1; it < 16; ++it) {
        const int t = t0 + it;
        const bool hasnext = (it < 15);

        // prefetch em[t+1]
        float evn = 0.f;
        if (tid < KDIM && hasnext) evn = emb[(t + 1) * KDIM + tid];

        #pragma unroll
        for (int r = 0; r < 2; ++r)
            #pragma unroll
            for (int tj = 0; tj < 8; ++tj)
                acc[r][tj] = (floatx4){0.f, 0.f, 0.f, 0.f};

        // ---- C = P * E : A from LDS, B from global (L2-hot) ----
        #pragma unroll
        for (int ks = 0; ks < 4; ++ks) {
            half8 a0 = *(const half8*)&Alds[((tr0 * 16 + ks * 4 + quad) * 16 + lm) * 8];
            half8 a1 = *(const half8*)&Alds[((tr1 * 16 + ks * 4 + quad) * 16 + lm) * 8];
            #pragma unroll
            for (int tj = 0; tj < 8; ++tj) {
                half8 bb = *(const half8*)&Ebl[((tj * 16 + ks * 4 + quad) * 16 + lm) * 8];
                acc[0][tj] = __builtin_amdgcn_mfma_f32_16x16x32_f16(a0, bb, acc[0][tj], 0, 0, 0);
                acc[1][tj] = __builtin_amdgcn_mfma_f32_16x16x32_f16(a1, bb, acc[1][tj], 0, 0, 0);
            }
        }

        // next-step em max (off critical path)
        float mn = (tid < KDIM && hasnext) ? evn : -INFINITY;
        #pragma unroll
        for (int o = 32; o; o >>= 1) mn = fmaxf(mn, __shfl_xor(mn, o));
        if (lane == 0 && w < 2) slotE[it & 1][w] = mn;

        // local max of col-scaled C
        const float* gc = gbuf[it & 1];
        float lmax = 0.f;
        #pragma unroll
        for (int tj = 0; tj < 8; ++tj) {
            const float gcol = gc[tj * 16 + lm];
            #pragma unroll
            for (int r = 0; r < 2; ++r) {
                floatx4 v = acc[r][tj];
                float m4 = fmaxf(fmaxf(v.x, v.y), fmaxf(v.z, v.w));
                lmax = fmaxf(lmax, gcol * m4);
            }
        }
        #pragma unroll
        for (int o = 32; o; o >>= 1) lmax = fmaxf(lmax, __shfl_xor(lmax, o));
        if (lane == 0) slotV[w] = lmax;
        __syncthreads();                                   // barrier 1

        const float rr = fmaxf(fmaxf(slotV[0], slotV[1]), fmaxf(slotV[2], slotV[3]));
        const float rinv = 1.0f / rr;
        if (tid < KDIM && hasnext) {
            const float mEn = fmaxf(slotE[it & 1][0], slotE[it & 1][1]);
            gbuf[(it + 1) & 1][tid] = __expf(evn - mEn);
            if (tid == 0) S += mEn;
        }
        if (tid == 0) S += mT + __logf(rr);

        // write normalized P back to A-layout
        #pragma unroll
        for (int tj = 0; tj < 8; ++tj) {
            const float gs = gc[tj * 16 + lm] * rinv;
            const int j_ = tj * 16 + lm;
            const int jhi = (j_ >> 3), jlo = (j_ & 7);
            #pragma unroll
            for (int r = 0; r < 2; ++r) {
                const int ti = 2 * w + r;
                #pragma unroll
                for (int q = 0; q < 4; ++q) {
                    float v = acc[r][tj][q] * gs;
                    Alds[((ti * 16 + jhi) * 16 + (quad * 4 + q)) * 8 + jlo] = (_Float16)v;
                }
            }
        }
        __syncthreads();                                   // barrier 2
    }

    // --- write P (row-major f16) + S ---
    _Float16* Pc = Pst + ((size_t)(b * NMAT + c)) * 16384;
    for (int s = 0; s < 8; ++s) {
        int e8 = tid + s * 256;                  // 0..2047
        int i_ = e8 >> 4, jg = e8 & 15;
        half8 v = *(const half8*)&Alds[(((i_ >> 4) * 16 + jg) * 16 + (i_ & 15)) * 8];
        *(half8*)&Pc[i_ * 128 + jg * 8] = v;
    }
    if (tid == 0) Sout[b * NMAT + c] = S;
}

// ================= phase 2: sequential scan over chunk matrices =================
// Rewritten R4: chunk matrix in registers (4x half8/thread), register prefetch of
// next chunk, shfl-xor k-reduction, exp/log off the critical path.
// State: normalized p (max=1) in LDS + scalar log-offset L.
//   q = p*P ; r = max q ; p' = q/r ; aEnter[c+1] = L + S_c + log q ; L += S_c + log r
__global__ __launch_bounds__(512, 2) void crf_scan(
    const float* __restrict__ em, const _Float16* __restrict__ Pst,
    const float* __restrict__ S, float* __restrict__ aEnter)
{
    const int b   = blockIdx.x;
    const int tid = threadIdx.x;
    const int kt  = tid & 31;          // k = kt*4 + i
    const int jg  = tid >> 5;          // j = jg*8 + r
    const int lane = tid & 63;
    const int wv   = tid >> 6;
    const bool owner = (kt == 0);      // lanes 0 and 32 of each wave

    __shared__ __align__(16) float p_lds[KDIM];
    __shared__ float slotQ[16];
    __shared__ float islot[2];

    float* aeb = aEnter + (size_t)b * NCH * KDIM;

    // ---- init: a0 = em[b,0,:]; p = exp(a0 - m0); L = m0 ----
    float a0 = 0.f;
    if (tid < KDIM) a0 = em[(size_t)b * TLEN * KDIM + tid];
    {
        float v = (tid < KDIM) ? a0 : -INFINITY;
        #pragma unroll
        for (int o = 32; o; o >>= 1) v = fmaxf(v, __shfl_xor(v, o));
        if (lane == 0 && wv < 2) islot[wv] = v;
    }
    __syncthreads();
    float L = fmaxf(islot[0], islot[1]);       // m0, uniform
    if (tid < KDIM) {
        aeb[tid] = a0;
        p_lds[tid] = __expf(a0 - L);
    }

    // preload chunk 0 into registers
    const _Float16* PbBase = Pst + (size_t)b * NMAT * 16384;
    half8 Pr[4];
    #pragma unroll
    for (int i = 0; i < 4; ++i)
        Pr[i] = *(const half8*)&PbBase[(kt * 4 + i) * KDIM + jg * 8];
    __syncthreads();                           // p_lds ready

    for (int c = 0; c < NMAT; ++c) {
        // register-prefetch next chunk (no dependence on this step)
        const _Float16* Pn = PbBase + (size_t)((c + 1 < NMAT) ? (c + 1) : c) * 16384;
        half8 Pf[4];
        #pragma unroll
        for (int i = 0; i < 4; ++i)
            Pf[i] = *(const half8*)&Pn[(kt * 4 + i) * KDIM + jg * 8];

        const float s_c = S[b * NMAT + c];

        // ---- matvec: acc[r] = sum_i p[kt*4+i] * P[kt*4+i][jg*8+r] ----
        const float4 pv = *(const float4*)&p_lds[kt * 4];
        float acc[8];
        #pragma unroll
        for (int r = 0; r < 8; ++r) acc[r] = 0.f;
        #pragma unroll
        for (int r = 0; r < 8; ++r) {
            acc[r] = fmaf(pv.x, (float)Pr[0][r], acc[r]);
            acc[r] = fmaf(pv.y, (float)Pr[1][r], acc[r]);
            acc[r] = fmaf(pv.z, (float)Pr[2][r], acc[r]);
            acc[r] = fmaf(pv.w, (float)Pr[3][r], acc[r]);
        }
        // reduce over kt within each 32-lane half
        #pragma unroll
        for (int o = 1; o < 32; o <<= 1) {
            #pragma unroll
            for (int r = 0; r < 8; ++r) acc[r] += __shfl_xor(acc[r], o);
        }
        if (owner) {
            float mx = acc[0];
            #pragma unroll
            for (int r = 1; r < 8; ++r) mx = fmaxf(mx, acc[r]);
            slotQ[jg] = mx;
        }
        __syncthreads();                       // barrier A: slotQ ready, p_lds consumed

        float rr = slotQ[0];
        #pragma unroll
        for (int s = 1; s < 16; ++s) rr = fmaxf(rr, slotQ[s]);
        const float rinv = 1.0f / rr;
        const float Lq = L + s_c;              // aEnter = Lq + log q
        if (owner) {
            float4 pa, pb;
            pa.x = acc[0] * rinv; pa.y = acc[1] * rinv;
            pa.z = acc[2] * rinv; pa.w = acc[3] * rinv;
            pb.x = acc[4] * rinv; pb.y = acc[5] * rinv;
            pb.z = acc[6] * rinv; pb.w = acc[7] * rinv;
            *(float4*)&p_lds[jg * 8]     = pa;
            *(float4*)&p_lds[jg * 8 + 4] = pb;
            float4 oa, ob;
            oa.x = Lq + __logf(acc[0]); oa.y = Lq + __logf(acc[1]);
            oa.z = Lq + __logf(acc[2]); oa.w = Lq + __logf(acc[3]);
            ob.x = Lq + __logf(acc[4]); ob.y = Lq + __logf(acc[5]);
            ob.z = Lq + __logf(acc[6]); ob.w = Lq + __logf(acc[7]);
            *(float4*)&aeb[(c + 1) * KDIM + jg * 8]     = oa;
            *(float4*)&aeb[(c + 1) * KDIM + jg * 8 + 4] = ob;
        }
        L = Lq + __logf(rr);
        #pragma unroll
        for (int i = 0; i < 4; ++i) Pr[i] = Pf[i];
        __syncthreads();                       // barrier B: p_lds ready for next step
    }
}

// ================= phase 3: fp32 replay within chunks + logZ =================
__global__ __launch_bounds__(256, 2) void crf_replay(
    const float* __restrict__ trans, const float* __restrict__ em,
    const int* __restrict__ seq_lens, const float* __restrict__ aEnter,
    float* __restrict__ alpha, float* __restrict__ logZ)
{
    const int c = blockIdx.x, b = blockIdx.y;
    const int tid = threadIdx.x;
    const int j = tid & 127, h = tid >> 7;

    __shared__ __align__(16) float p_lds[2][KDIM];
    __shared__ float part[2][KDIM];
    __shared__ float mslot[2][2];
    __shared__ float red[2];

    float Ereg[64];
    #pragma unroll
    for (int k = 0; k < 64; ++k) Ereg[k] = __expf(trans[(h * 64 + k) * KDIM + j]);

    const int len = seq_lens[b];
    const float* emb = em + (size_t)b * TLEN * KDIM;
    float* outb = alpha + (size_t)b * TLEN * KDIM;

    float a = 0.f, last_a = 0.f;
    if (h == 0) a = aEnter[((size_t)b * NCH + c) * KDIM + j];
    if (c == 0 && h == 0) {
        outb[j] = a;
        if (len == 1) last_a = a;
    }
    {
        float v = (h == 0) ? a : -INFINITY;
        #pragma unroll
        for (int o = 32; o; o >>= 1) v = fmaxf(v, __shfl_xor(v, o));
        if ((tid & 63) == 0 && h == 0) mslot[0][tid >> 6] = v;
    }
    __syncthreads();
    float m = fmaxf(mslot[0][0], mslot[0][1]);

    const int t_begin = c * CH_L + 1;
    const int t_end = (c == NCH - 1) ? (TLEN - 1) : (c * CH_L + CH_L);

    for (int t = t_begin; t <= t_end; ++t) {
        const int par = t & 1;
        float em_t = 0.f;
        if (h == 0) {
            em_t = emb[t * KDIM + j];
            p_lds[par][j] = __expf(a - m);
            float v = a;
            #pragma unroll
            for (int o = 32; o; o >>= 1) v = fmaxf(v, __shfl_xor(v, o));
            if ((tid & 63) == 0) mslot[par][tid >> 6] = v;
        }
        __syncthreads();                                   // barrier 1
        float acc0 = 0.f, acc1 = 0.f, acc2 = 0.f, acc3 = 0.f;
        const float4* p4 = (const float4*)&p_lds[par][h * 64];
        #pragma unroll
        for (int k4 = 0; k4 < 16; ++k4) {
            float4 pv = p4[k4];
            acc0 = fmaf(pv.x, Ereg[4 * k4 + 0], acc0);
            acc1 = fmaf(pv.y, Ereg[4 * k4 + 1], acc1);
            acc2 = fmaf(pv.z, Ereg[4 * k4 + 2], acc2);
            acc3 = fmaf(pv.w, Ereg[4 * k4 + 3], acc3);
        }
        if (h) part[par][j] = (acc0 + acc1) + (acc2 + acc3);
        __syncthreads();                                   // barrier 2
        if (h == 0) {
            const float q = ((acc0 + acc1) + (acc2 + acc3)) + part[par][j];
            a = em_t + m + __logf(q);
            outb[t * KDIM + j] = a;
            if (t == len - 1) last_a = a;
            m = fmaxf(mslot[par][0], mslot[par][1]);
        }
    }

    const bool blockowns = (len == 1) ? (c == 0) : (((len - 2) >> 4) == c);
    __syncthreads();
    if (blockowns) {
        float v = (h == 0) ? last_a : -INFINITY;
        #pragma unroll
        for (int o = 32; o; o >>= 1) v = fmaxf(v, __shfl_xor(v, o));
        if ((tid & 63) == 0 && h == 0) mslot[0][tid >> 6] = v;
        __syncthreads();
        const float m2 = fmaxf(mslot[0][0], mslot[0][1]);
        float e = (h == 0) ? __expf(last_a - m2) : 0.f;
        #pragma unroll
        for (int o = 32; o; o >>= 1) e += __shfl_xor(e, o);
        if ((tid & 63) == 0 && h == 0) red[tid >> 6] = e;
        __syncthreads();
        if (tid == 0) logZ[b] = m2 + __logf(red[0] + red[1]);
    }
}

// ================= fallback (proven R1 kernel) for small ws =================
__global__ __launch_bounds__(256) void crf_forward_fallback(
    const float* __restrict__ trans, const float* __restrict__ em,
    const int* __restrict__ seq_lens, float* __restrict__ alpha_out,
    float* __restrict__ logZ_out)
{
    const int b = blockIdx.x;
    const int tid = threadIdx.x;
    const int j = tid & (KDIM - 1);
    const int h = tid >> 7;

    __shared__ __align__(16) float p_lds[KDIM];
    __shared__ float part[KDIM];
    __shared__ float red[8];

    float Ereg[64];
    #pragma unroll
    for (int k = 0; k < 64; ++k) Ereg[k] = __expf(trans[(h * 64 + k) * KDIM + j]);

    const int len = seq_lens[b];
    const float* emb = em + (size_t)b * TLEN * KDIM;
    float* outb = alpha_out + (size_t)b * TLEN * KDIM;

    float a = 0.f, last_a = 0.f;
    if (h == 0) {
        a = emb[j];
        outb[j] = a;
        if (len == 1) last_a = a;
    }
    for (int t = 1; t < TLEN; ++t) {
        {
            float v = (h == 0) ? a : -INFINITY;
            #pragma unroll
            for (int o = 32; o >= 1; o >>= 1) v = fmaxf(v, __shfl_xor(v, o));
            if ((tid & 63) == 0) red[tid >> 6] = v;
        }
        __syncthreads();
        const float m = fmaxf(red[0], red[1]);
        if (h == 0) p_lds[j] = __expf(a - m);
        __syncthreads();
        float em_t = 0.f;
        if (h == 0) em_t = emb[t * KDIM + j];
        float acc0 = 0.f, acc1 = 0.f, acc2 = 0.f, acc3 = 0.f;
        const float4* p4 = (const float4*)(p_lds + h * 64);
        #pragma unroll
        for (int k4 = 0; k4 < 16; ++k4) {
            float4 pv = p4[k4];
            acc0 = fmaf(pv.x, Ereg[4 * k4 + 0], acc0);
            acc1 = fmaf(pv.y, Ereg[4 * k4 + 1], acc1);
            acc2 = fmaf(pv.z, Ereg[4 * k4 + 2], acc2);
            acc3 = fmaf(pv.w, Ereg[4 * k4 + 3], acc3);
        }
        const float acc = (acc0 + acc1) + (acc2 + acc3);
        if (h == 1) part[j] = acc;
        __syncthreads();
        if (h == 0) {
            const float q = acc + part[j];
            a = em_t + m + __logf(q);
            outb[t * KDIM + j] = a;
            if (t == len - 1) last_a = a;
        }
    }
    {
        float v = (h == 0) ? last_a : -INFINITY;
        #pragma unroll
        for (int o = 32; o >= 1; o >>= 1) v = fmaxf(v, __shfl_xor(v, o));
        if ((tid & 63) == 0) red[tid >> 6] = v;
    }
    __syncthreads();
    const float m2 = fmaxf(red[0], red[1]);
    float e = (h == 0) ? __expf(last_a - m2) : 0.f;
    #pragma unroll
    for (int o = 32; o >= 1; o >>= 1) e += __shfl_xor(e, o);
    if ((tid & 63) == 0) red[4 + (tid >> 6)] = e;
    __syncthreads();
    if (tid == 0) logZ_out[b] = m2 + logf(red[4] + red[5]);
}

extern "C" void kernel_launch(void* const* d_in, const int* in_sizes, int n_in,
                              void* d_out, int out_size, void* d_ws, size_t ws_size,
                              hipStream_t stream) {
    const float* trans    = (const float*)d_in[0];   // K*K
    const float* em       = (const float*)d_in[1];   // B*T*K
    const int*   seq_lens = (const int*)d_in[2];     // B

    float* alpha_out = (float*)d_out;                            // B*T*K
    float* logZ_out  = alpha_out + (size_t)BATCH * TLEN * KDIM;  // B

    if (ws_size < (size_t)WS_NEED) {
        crf_forward_fallback<<<BATCH, 256, 0, stream>>>(trans, em, seq_lens,
                                                        alpha_out, logZ_out);
        return;
    }

    char* ws = (char*)d_ws;
    _Float16* Pst  = (_Float16*)(ws + WS_PST);
    _Float16* Ebl  = (_Float16*)(ws + WS_EBL);
    float*    Slog = (float*)(ws + WS_SLOG);
    float*    aEnt = (float*)(ws + WS_AENT);
    float*    mTws = (float*)(ws + WS_MT);

    crf_prepE<<<1, 256, 0, stream>>>(trans, Ebl, mTws);
    crf_chunkmat<<<dim3(NMAT, BATCH), 256, 0, stream>>>(trans, em, Ebl, mTws, Pst, Slog);
    crf_scan<<<BATCH, 512, 0, stream>>>(em, Pst, Slog, aEnt);
    crf_replay<<<dim3(NCH, BATCH), 256, 0, stream>>>(trans, em, seq_lens, aEnt,
                                                     alpha_out, logZ_out);
}

// Round 5
// 207.701 us; speedup vs baseline: 2.5119x; 1.3117x over previous
//
#include <hip/hip_runtime.h>
#include <math.h>

#define KDIM 128
#define TLEN 512
#define BATCH 16
#define CH_L 16
#define NCH 32           // chunks per batch (phase 3)
#define NMAT 31          // chunk matrices (phase 1/2): chunk c covers t in [16c+1, 16c+16]

typedef _Float16 half8 __attribute__((ext_vector_type(8)));
typedef _Float16 half4 __attribute__((ext_vector_type(4)));
typedef float floatx4 __attribute__((ext_vector_type(4)));

// ---------------- ws layout (bytes) ----------------
// PST : f16 [BATCH][NMAT][128][128] row-major P[enter][exit]
// ETA : f16 E^T in A-frag layout (32768 B)
// ETB : f16 E^T in padded B-frag layout, row pitch 136 halfs (34816 B)
#define WS_PST   0
#define WS_ETA   16252928
#define WS_ETB   16285696
#define WS_SLOG  16320512
#define WS_AENT  16322496
#define WS_MT    16584640
#define WS_NEED  16584644

// Frag conventions (validated R2-R4, guide §3):
//  A-frag tile(mt,kt): lane(quad,lm) holds A[mt*16+lm][kt*32+quad*8 .. +8]
//  B-frag tile(kt,nt): lane(quad,lm) holds B[kt*32+quad*8 .. +8][nt*16+lm]
//  C/D  tile(mt,nt):   lane(quad,lm) reg q = C[mt*16+quad*4+q][nt*16+lm]
// Storage:
//  EtA halfs: aofs(m,k) = (((m>>4)*4 + (k>>5))*4 + ((k>>3)&3))*16 + (m&15))*8 + (k&7)
//  padded B layout halfs: bofs(k,n) = ((n>>4)*16 + (k>>3))*136 + (n&15)*8 + (k&7)
//   (pitch 136 = 128 + 8 pad halfs per (n-tile,k-oct) row -> 4-bank stagger)

// ================= prep: build EtA (A-layout) + EtB (padded B-layout) =================
__global__ __launch_bounds__(256) void crf_prep2(const float* __restrict__ trans,
                                                 _Float16* __restrict__ EtA,
                                                 _Float16* __restrict__ EtB,
                                                 float* __restrict__ mTout)
{
    const int tid = threadIdx.x;
    __shared__ float slot[4];
    __shared__ __align__(16) _Float16 sb[17408];

    float mt = -INFINITY;
    for (int s = 0; s < 64; ++s) mt = fmaxf(mt, trans[tid + s * 256]);
    #pragma unroll
    for (int o = 32; o; o >>= 1) mt = fmaxf(mt, __shfl_xor(mt, o));
    if ((tid & 63) == 0) slot[tid >> 6] = mt;
    __syncthreads();
    const float mT = fmaxf(fmaxf(slot[0], slot[1]), fmaxf(slot[2], slot[3]));

    // --- EtA = E^T in A-layout: A[m][k] = E[k][m] = exp(trans[k*128+m]-mT) ---
    for (int s = 0; s < 64; ++s) {
        int e = tid + s * 256;
        int k = e >> 7, m = e & 127;
        float v = __expf(trans[e] - mT);
        sb[((((m >> 4) * 4 + (k >> 5)) * 4 + ((k >> 3) & 3)) * 16 + (m & 15)) * 8 + (k & 7)] =
            (_Float16)v;
    }
    __syncthreads();
    for (int s = 0; s < 8; ++s) {
        int x = (tid + s * 256) * 8;
        *(half8*)&EtA[x] = *(const half8*)&sb[x];
    }
    __syncthreads();

    // --- EtB: element (k=j, n=i) = E[i][j] = exp(trans[i*128+j]-mT), padded B-layout ---
    for (int s = 0; s < 64; ++s) {
        int e = tid + s * 256;
        int i = e >> 7, j = e & 127;
        float v = __expf(trans[e] - mT);
        sb[((i >> 4) * 16 + (j >> 3)) * 136 + (i & 15) * 8 + (j & 7)] = (_Float16)v;
    }
    __syncthreads();
    for (int s = 0; s < 9; ++s) {
        int g = tid + s * 256;
        if (g < 2176) {
            int x = g * 8;
            *(half8*)&EtB[x] = *(const half8*)&sb[x];
        }
    }
    if (tid == 0) mTout[0] = mT;
}

// ================= phase 1: chunk products, transposed iteration =================
// Pt = P_chunk^T maintained in LDS (padded B-layout).
// Iteration: Pt <- diag(g_t) * E^T * Pt ; A = E^T constant in registers.
__global__ __launch_bounds__(256, 2) void crf_chunkmat2(
    const float* __restrict__ em,
    const _Float16* __restrict__ EtA, const _Float16* __restrict__ EtB,
    const float* __restrict__ mTws,
    _Float16* __restrict__ Pst, float* __restrict__ Sout)
{
    const int c = blockIdx.x;     // 0..NMAT-1
    const int b = blockIdx.y;
    const int tid = threadIdx.x;
    const int w = tid >> 6, lane = tid & 63;
    const int quad = lane >> 4, lm = lane & 15;

    __shared__ __align__(16) _Float16 buf[17408];   // 34.8 KB padded B-layout
    __shared__ float gbuf[2][KDIM];
    __shared__ float slotV[4];
    __shared__ float slotE[2][2];

    const float mT = mTws[0];
    const int t0 = c * CH_L + 1;
    const float* emb = em + (size_t)b * TLEN * KDIM;

    // --- A fragments (E^T), loop-invariant: 8 x half8 = 32 VGPRs ---
    half8 EA[2][4];
    #pragma unroll
    for (int r = 0; r < 2; ++r) {
        const int tr = 2 * w + r;
        #pragma unroll
        for (int kt = 0; kt < 4; ++kt)
            EA[r][kt] = *(const half8*)&EtA[(((tr * 4 + kt) * 4 + quad) * 16 + lm) * 8];
    }

    // --- em maxes + g for t0 and t0+1 ---
    float ev0 = 0.f, ev1 = 0.f;
    if (tid < KDIM) {
        ev0 = emb[t0 * KDIM + tid];
        ev1 = emb[(t0 + 1) * KDIM + tid];
    }
    float m0 = (tid < KDIM) ? ev0 : -INFINITY;
    #pragma unroll
    for (int o = 32; o; o >>= 1) m0 = fmaxf(m0, __shfl_xor(m0, o));
    float m1 = (tid < KDIM) ? ev1 : -INFINITY;
    #pragma unroll
    for (int o = 32; o; o >>= 1) m1 = fmaxf(m1, __shfl_xor(m1, o));
    if (lane == 0 && w < 2) { slotE[0][w] = m0; slotE[1][w] = m1; }
    __syncthreads();
    const float mE0 = fmaxf(slotE[0][0], slotE[0][1]);
    const float mE1 = fmaxf(slotE[1][0], slotE[1][1]);
    if (tid < KDIM) {
        gbuf[0][tid] = __expf(ev0 - mE0);
        gbuf[1][tid] = __expf(ev1 - mE1);
    }
    __syncthreads();

    // --- init buf = M_t0^T = diag(g0)*E^T : group-wise copy+scale of EtB ---
    for (int s = 0; s < 8; ++s) {
        int g = tid + s * 256;                    // 2048 data groups
        int row = g >> 4, nl = g & 15;
        int addr = row * 136 + nl * 8;
        int j0 = (row & 15) * 8;                  // j-octet of this group
        half8 e = *(const half8*)&EtB[addr];
        const float* g0p = &gbuf[0][j0];
        half8 o;
        #pragma unroll
        for (int x = 0; x < 8; ++x) o[x] = (_Float16)((float)e[x] * g0p[x]);
        *(half8*)&buf[addr] = o;
    }
    float S = mT + mE0 + mE1;     // only thread 0's copy matters
    __syncthreads();

    floatx4 acc[2][8];

    for (int it = 1; it < 16; ++it) {
        const int t = t0 + it;
        const bool hasnext = (it < 15);

        float evn = 0.f;
        if (tid < KDIM && hasnext) evn = emb[(t + 1) * KDIM + tid];

        #pragma unroll
        for (int r = 0; r < 2; ++r)
            #pragma unroll
            for (int nt = 0; nt < 8; ++nt)
                acc[r][nt] = (floatx4){0.f, 0.f, 0.f, 0.f};

        // ---- C = E^T * Pt : A regs, B from LDS ----
        #pragma unroll
        for (int kt = 0; kt < 4; ++kt) {
            #pragma unroll
            for (int nt = 0; nt < 8; ++nt) {
                half8 bb = *(const half8*)&buf[(nt * 16 + kt * 4 + quad) * 136 + lm * 8];
                acc[0][nt] = __builtin_amdgcn_mfma_f32_16x16x32_f16(EA[0][kt], bb, acc[0][nt], 0, 0, 0);
                acc[1][nt] = __builtin_amdgcn_mfma_f32_16x16x32_f16(EA[1][kt], bb, acc[1][nt], 0, 0, 0);
            }
        }

        // next-step em max (off critical path)
        float mn = (tid < KDIM && hasnext) ? evn : -INFINITY;
        #pragma unroll
        for (int o = 32; o; o >>= 1) mn = fmaxf(mn, __shfl_xor(mn, o));
        if (lane == 0 && w < 2) slotE[it & 1][w] = mn;

        // row-scale factors g[j], j = tr*16 + quad*4 + q
        const float* gc = gbuf[it & 1];
        const float4 gr0 = *(const float4*)&gc[(2 * w + 0) * 16 + quad * 4];
        const float4 gr1 = *(const float4*)&gc[(2 * w + 1) * 16 + quad * 4];

        float lmax = 0.f;
        #pragma unroll
        for (int nt = 0; nt < 8; ++nt) {
            floatx4 v0 = acc[0][nt], v1 = acc[1][nt];
            float a0 = fmaxf(fmaxf(v0.x * gr0.x, v0.y * gr0.y), fmaxf(v0.z * gr0.z, v0.w * gr0.w));
            float a1 = fmaxf(fmaxf(v1.x * gr1.x, v1.y * gr1.y), fmaxf(v1.z * gr1.z, v1.w * gr1.w));
            lmax = fmaxf(lmax, fmaxf(a0, a1));
        }
        #pragma unroll
        for (int o = 32; o; o >>= 1) lmax = fmaxf(lmax, __shfl_xor(lmax, o));
        if (lane == 0) slotV[w] = lmax;
        __syncthreads();                                   // barrier 1

        const float rr = fmaxf(fmaxf(slotV[0], slotV[1]), fmaxf(slotV[2], slotV[3]));
        const float rinv = 1.0f / rr;
        if (tid < KDIM && hasnext) {
            const float mEn = fmaxf(slotE[it & 1][0], slotE[it & 1][1]);
            gbuf[(it + 1) & 1][tid] = __expf(evn - mEn);
            if (tid == 0) S += mEn;
        }
        if (tid == 0) S += mT + __logf(rr);

        // ---- write normalized diag(g)*C back to B-layout: 16x ds_write_b64 ----
        const float4 s0 = {gr0.x * rinv, gr0.y * rinv, gr0.z * rinv, gr0.w * rinv};
        const float4 s1 = {gr1.x * rinv, gr1.y * rinv, gr1.z * rinv, gr1.w * rinv};
        const int jlb = (quad & 1) * 4;
        #pragma unroll
        for (int r = 0; r < 2; ++r) {
            const int tr = 2 * w + r;
            const int kh = tr * 2 + (quad >> 1);
            const float4 sc = r ? s1 : s0;
            #pragma unroll
            for (int nt = 0; nt < 8; ++nt) {
                const floatx4 v = acc[r][nt];
                half4 o;
                o[0] = (_Float16)(v.x * sc.x);
                o[1] = (_Float16)(v.y * sc.y);
                o[2] = (_Float16)(v.z * sc.z);
                o[3] = (_Float16)(v.w * sc.w);
                *(half4*)&buf[(nt * 16 + kh) * 136 + lm * 8 + jlb] = o;
            }
        }
        __syncthreads();                                   // barrier 2
    }

    // --- store P row-major: B-layout half8 = P[enter=i][exit j-octet] ---
    _Float16* Pc = Pst + ((size_t)(b * NMAT + c)) * 16384;
    for (int s = 0; s < 8; ++s) {
        int o_ = tid + s * 256;                  // 0..2047
        int i = o_ >> 4, kh = o_ & 15;
        half8 v = *(const half8*)&buf[((i >> 4) * 16 + kh) * 136 + (i & 15) * 8];
        *(half8*)&Pc[i * 128 + kh * 8] = v;
    }
    if (tid == 0) Sout[b * NMAT + c] = S;
}

// ================= phase 2: sequential scan over chunk matrices (R4, proven) ====
__global__ __launch_bounds__(512, 2) void crf_scan(
    const float* __restrict__ em, const _Float16* __restrict__ Pst,
    const float* __restrict__ S, float* __restrict__ aEnter)
{
    const int b   = blockIdx.x;
    const int tid = threadIdx.x;
    const int kt  = tid & 31;          // k = kt*4 + i
    const int jg  = tid >> 5;          // j = jg*8 + r
    const int lane = tid & 63;
    const int wv   = tid >> 6;
    const bool owner = (kt == 0);

    __shared__ __align__(16) float p_lds[KDIM];
    __shared__ float slotQ[16];
    __shared__ float islot[2];

    float* aeb = aEnter + (size_t)b * NCH * KDIM;

    float a0 = 0.f;
    if (tid < KDIM) a0 = em[(size_t)b * TLEN * KDIM + tid];
    {
        float v = (tid < KDIM) ? a0 : -INFINITY;
        #pragma unroll
        for (int o = 32; o; o >>= 1) v = fmaxf(v, __shfl_xor(v, o));
        if (lane == 0 && wv < 2) islot[wv] = v;
    }
    __syncthreads();
    float L = fmaxf(islot[0], islot[1]);
    if (tid < KDIM) {
        aeb[tid] = a0;
        p_lds[tid] = __expf(a0 - L);
    }

    const _Float16* PbBase = Pst + (size_t)b * NMAT * 16384;
    half8 Pr[4];
    #pragma unroll
    for (int i = 0; i < 4; ++i)
        Pr[i] = *(const half8*)&PbBase[(kt * 4 + i) * KDIM + jg * 8];
    __syncthreads();

    for (int c = 0; c < NMAT; ++c) {
        const _Float16* Pn = PbBase + (size_t)((c + 1 < NMAT) ? (c + 1) : c) * 16384;
        half8 Pf[4];
        #pragma unroll
        for (int i = 0; i < 4; ++i)
            Pf[i] = *(const half8*)&Pn[(kt * 4 + i) * KDIM + jg * 8];

        const float s_c = S[b * NMAT + c];

        const float4 pv = *(const float4*)&p_lds[kt * 4];
        float acc[8];
        #pragma unroll
        for (int r = 0; r < 8; ++r) acc[r] = 0.f;
        #pragma unroll
        for (int r = 0; r < 8; ++r) {
            acc[r] = fmaf(pv.x, (float)Pr[0][r], acc[r]);
            acc[r] = fmaf(pv.y, (float)Pr[1][r], acc[r]);
            acc[r] = fmaf(pv.z, (float)Pr[2][r], acc[r]);
            acc[r] = fmaf(pv.w, (float)Pr[3][r], acc[r]);
        }
        #pragma unroll
        for (int o = 1; o < 32; o <<= 1) {
            #pragma unroll
            for (int r = 0; r < 8; ++r) acc[r] += __shfl_xor(acc[r], o);
        }
        if (owner) {
            float mx = acc[0];
            #pragma unroll
            for (int r = 1; r < 8; ++r) mx = fmaxf(mx, acc[r]);
            slotQ[jg] = mx;
        }
        __syncthreads();

        float rr = slotQ[0];
        #pragma unroll
        for (int s = 1; s < 16; ++s) rr = fmaxf(rr, slotQ[s]);
        const float rinv = 1.0f / rr;
        const float Lq = L + s_c;
        if (owner) {
            float4 pa, pb;
            pa.x = acc[0] * rinv; pa.y = acc[1] * rinv;
            pa.z = acc[2] * rinv; pa.w = acc[3] * rinv;
            pb.x = acc[4] * rinv; pb.y = acc[5] * rinv;
            pb.z = acc[6] * rinv; pb.w = acc[7] * rinv;
            *(float4*)&p_lds[jg * 8]     = pa;
            *(float4*)&p_lds[jg * 8 + 4] = pb;
            float4 oa, ob;
            oa.x = Lq + __logf(acc[0]); oa.y = Lq + __logf(acc[1]);
            oa.z = Lq + __logf(acc[2]); oa.w = Lq + __logf(acc[3]);
            ob.x = Lq + __logf(acc[4]); ob.y = Lq + __logf(acc[5]);
            ob.z = Lq + __logf(acc[6]); ob.w = Lq + __logf(acc[7]);
            *(float4*)&aeb[(c + 1) * KDIM + jg * 8]     = oa;
            *(float4*)&aeb[(c + 1) * KDIM + jg * 8 + 4] = ob;
        }
        L = Lq + __logf(rr);
        #pragma unroll
        for (int i = 0; i < 4; ++i) Pr[i] = Pf[i];
        __syncthreads();
    }
}

// ================= phase 3: fp32 replay within chunks + logZ (R4, proven) =======
__global__ __launch_bounds__(256, 2) void crf_replay(
    const float* __restrict__ trans, const float* __restrict__ em,
    const int* __restrict__ seq_lens, const float* __restrict__ aEnter,
    float* __restrict__ alpha, float* __restrict__ logZ)
{
    const int c = blockIdx.x, b = blockIdx.y;
    const int tid = threadIdx.x;
    const int j = tid & 127, h = tid >> 7;

    __shared__ __align__(16) float p_lds[2][KDIM];
    __shared__ float part[2][KDIM];
    __shared__ float mslot[2][2];
    __shared__ float red[2];

    float Ereg[64];
    #pragma unroll
    for (int k = 0; k < 64; ++k) Ereg[k] = __expf(trans[(h * 64 + k) * KDIM + j]);

    const int len = seq_lens[b];
    const float* emb = em + (size_t)b * TLEN * KDIM;
    float* outb = alpha + (size_t)b * TLEN * KDIM;

    float a = 0.f, last_a = 0.f;
    if (h == 0) a = aEnter[((size_t)b * NCH + c) * KDIM + j];
    if (c == 0 && h == 0) {
        outb[j] = a;
        if (len == 1) last_a = a;
    }
    {
        float v = (h == 0) ? a : -INFINITY;
        #pragma unroll
        for (int o = 32; o; o >>= 1) v = fmaxf(v, __shfl_xor(v, o));
        if ((tid & 63) == 0 && h == 0) mslot[0][tid >> 6] = v;
    }
    __syncthreads();
    float m = fmaxf(mslot[0][0], mslot[0][1]);

    const int t_begin = c * CH_L + 1;
    const int t_end = (c == NCH - 1) ? (TLEN - 1) : (c * CH_L + CH_L);

    for (int t = t_begin; t <= t_end; ++t) {
        const int par = t & 1;
        float em_t = 0.f;
        if (h == 0) {
            em_t = emb[t * KDIM + j];
            p_lds[par][j] = __expf(a - m);
            float v = a;
            #pragma unroll
            for (int o = 32; o; o >>= 1) v = fmaxf(v, __shfl_xor(v, o));
            if ((tid & 63) == 0) mslot[par][tid >> 6] = v;
        }
        __syncthreads();
        float acc0 = 0.f, acc1 = 0.f, acc2 = 0.f, acc3 = 0.f;
        const float4* p4 = (const float4*)&p_lds[par][h * 64];
        #pragma unroll
        for (int k4 = 0; k4 < 16; ++k4) {
            float4 pv = p4[k4];
            acc0 = fmaf(pv.x, Ereg[4 * k4 + 0], acc0);
            acc1 = fmaf(pv.y, Ereg[4 * k4 + 1], acc1);
            acc2 = fmaf(pv.z, Ereg[4 * k4 + 2], acc2);
            acc3 = fmaf(pv.w, Ereg[4 * k4 + 3], acc3);
        }
        if (h) part[par][j] = (acc0 + acc1) + (acc2 + acc3);
        __syncthreads();
        if (h == 0) {
            const float q = ((acc0 + acc1) + (acc2 + acc3)) + part[par][j];
            a = em_t + m + __logf(q);
            outb[t * KDIM + j] = a;
            if (t == len - 1) last_a = a;
            m = fmaxf(mslot[par][0], mslot[par][1]);
        }
    }

    const bool blockowns = (len == 1) ? (c == 0) : (((len - 2) >> 4) == c);
    __syncthreads();
    if (blockowns) {
        float v = (h == 0) ? last_a : -INFINITY;
        #pragma unroll
        for (int o = 32; o; o >>= 1) v = fmaxf(v, __shfl_xor(v, o));
        if ((tid & 63) == 0 && h == 0) mslot[0][tid >> 6] = v;
        __syncthreads();
        const float m2 = fmaxf(mslot[0][0], mslot[0][1]);
        float e = (h == 0) ? __expf(last_a - m2) : 0.f;
        #pragma unroll
        for (int o = 32; o; o >>= 1) e += __shfl_xor(e, o);
        if ((tid & 63) == 0 && h == 0) red[tid >> 6] = e;
        __syncthreads();
        if (tid == 0) logZ[b] = m2 + __logf(red[0] + red[1]);
    }
}

// ================= fallback (proven R1 kernel) for small ws =================
__global__ __launch_bounds__(256) void crf_forward_fallback(
    const float* __restrict__ trans, const float* __restrict__ em,
    const int* __restrict__ seq_lens, float* __restrict__ alpha_out,
    float* __restrict__ logZ_out)
{
    const int b = blockIdx.x;
    const int tid = threadIdx.x;
    const int j = tid & (KDIM - 1);
    const int h = tid >> 7;

    __shared__ __align__(16) float p_lds[KDIM];
    __shared__ float part[KDIM];
    __shared__ float red[8];

    float Ereg[64];
    #pragma unroll
    for (int k = 0; k < 64; ++k) Ereg[k] = __expf(trans[(h * 64 + k) * KDIM + j]);

    const int len = seq_lens[b];
    const float* emb = em + (size_t)b * TLEN * KDIM;
    float* outb = alpha_out + (size_t)b * TLEN * KDIM;

    float a = 0.f, last_a = 0.f;
    if (h == 0) {
        a = emb[j];
        outb[j] = a;
        if (len == 1) last_a = a;
    }
    for (int t = 1; t < TLEN; ++t) {
        {
            float v = (h == 0) ? a : -INFINITY;
            #pragma unroll
            for (int o = 32; o >= 1; o >>= 1) v = fmaxf(v, __shfl_xor(v, o));
            if ((tid & 63) == 0) red[tid >> 6] = v;
        }
        __syncthreads();
        const float m = fmaxf(red[0], red[1]);
        if (h == 0) p_lds[j] = __expf(a - m);
        __syncthreads();
        float em_t = 0.f;
        if (h == 0) em_t = emb[t * KDIM + j];
        float acc0 = 0.f, acc1 = 0.f, acc2 = 0.f, acc3 = 0.f;
        const float4* p4 = (const float4*)(p_lds + h * 64);
        #pragma unroll
        for (int k4 = 0; k4 < 16; ++k4) {
            float4 pv = p4[k4];
            acc0 = fmaf(pv.x, Ereg[4 * k4 + 0], acc0);
            acc1 = fmaf(pv.y, Ereg[4 * k4 + 1], acc1);
            acc2 = fmaf(pv.z, Ereg[4 * k4 + 2], acc2);
            acc3 = fmaf(pv.w, Ereg[4 * k4 + 3], acc3);
        }
        const float acc = (acc0 + acc1) + (acc2 + acc3);
        if (h == 1) part[j] = acc;
        __syncthreads();
        if (h == 0) {
            const float q = acc + part[j];
            a = em_t + m + __logf(q);
            outb[t * KDIM + j] = a;
            if (t == len - 1) last_a = a;
        }
    }
    {
        float v = (h == 0) ? last_a : -INFINITY;
        #pragma unroll
        for (int o = 32; o >= 1; o >>= 1) v = fmaxf(v, __shfl_xor(v, o));
        if ((tid & 63) == 0) red[tid >> 6] = v;
    }
    __syncthreads();
    const float m2 = fmaxf(red[0], red[1]);
    float e = (h == 0) ? __expf(last_a - m2) : 0.f;
    #pragma unroll
    for (int o = 32; o >= 1; o >>= 1) e += __shfl_xor(e, o);
    if ((tid & 63) == 0) red[4 + (tid >> 6)] = e;
    __syncthreads();
    if (tid == 0) logZ_out[b] = m2 + logf(red[4] + red[5]);
}

extern "C" void kernel_launch(void* const* d_in, const int* in_sizes, int n_in,
                              void* d_out, int out_size, void* d_ws, size_t ws_size,
                              hipStream_t stream) {
    const float* trans    = (const float*)d_in[0];   // K*K
    const float* em       = (const float*)d_in[1];   // B*T*K
    const int*   seq_lens = (const int*)d_in[2];     // B

    float* alpha_out = (float*)d_out;                            // B*T*K
    float* logZ_out  = alpha_out + (size_t)BATCH * TLEN * KDIM;  // B

    if (ws_size < (size_t)WS_NEED) {
        crf_forward_fallback<<<BATCH, 256, 0, stream>>>(trans, em, seq_lens,
                                                        alpha_out, logZ_out);
        return;
    }

    char* ws = (char*)d_ws;
    _Float16* Pst  = (_Float16*)(ws + WS_PST);
    _Float16* EtA  = (_Float16*)(ws + WS_ETA);
    _Float16* EtB  = (_Float16*)(ws + WS_ETB);
    float*    Slog = (float*)(ws + WS_SLOG);
    float*    aEnt = (float*)(ws + WS_AENT);
    float*    mTws = (float*)(ws + WS_MT);

    crf_prep2<<<1, 256, 0, stream>>>(trans, EtA, EtB, mTws);
    crf_chunkmat2<<<dim3(NMAT, BATCH), 256, 0, stream>>>(em, EtA, EtB, mTws, Pst, Slog);
    crf_scan<<<BATCH, 512, 0, stream>>>(em, Pst, Slog, aEnt);
    crf_replay<<<dim3(NCH, BATCH), 256, 0, stream>>>(trans, em, seq_lens, aEnt,
                                                     alpha_out, logZ_out);
}

// Round 6
// 177.661 us; speedup vs baseline: 2.9366x; 1.1691x over previous
//
#include <hip/hip_runtime.h>
#include <math.h>

#define KDIM 128
#define TLEN 512
#define BATCH 16
#define CH_L 16
#define NCH 32           // chunks per batch (phase 3)
#define NMAT 31          // chunk matrices: chunk c covers t in [16c+1, 16c+16]

typedef _Float16 half8 __attribute__((ext_vector_type(8)));
typedef _Float16 half4 __attribute__((ext_vector_type(4)));
typedef float floatx4 __attribute__((ext_vector_type(4)));

// ---------------- ws layout (bytes) ----------------
// PST : f16 [BATCH][NMAT] chunks; chunk layout: 16B unit u = K*128 + j holds
//       P[enter=K*8+e][exit=j], e=0..7  (K = enter-octet, j = exit state)
// ETA : f16 E^T in A-frag layout; ETB : f16 E^T in padded B-frag layout (pitch 136)
#define WS_PST   0
#define WS_ETA   16252928
#define WS_ETB   16285696
#define WS_SLOG  16320512
#define WS_AENT  16322496
#define WS_MT    16584640
#define WS_NEED  16584644

// Frag conventions (validated R2-R5):
//  A-frag tile(mt,kt): lane(quad,lm) holds A[mt*16+lm][kt*32+quad*8 .. +8]
//  B-frag tile(kt,nt): lane(quad,lm) holds B[kt*32+quad*8 .. +8][nt*16+lm]
//  C/D  tile(mt,nt):   lane(quad,lm) reg q = C[mt*16+quad*4+q][nt*16+lm]
//  padded B layout halfs: bofs(k,n) = ((n>>4)*16 + (k>>3))*136 + (n&15)*8 + (k&7)
//  buf(k,n) = Pt[exit=k][enter=n] = P[enter=n][exit=k]

// ================= prep: build EtA (A-layout) + EtB (padded B-layout) =================
__global__ __launch_bounds__(256) void crf_prep2(const float* __restrict__ trans,
                                                 _Float16* __restrict__ EtA,
                                                 _Float16* __restrict__ EtB,
                                                 float* __restrict__ mTout)
{
    const int tid = threadIdx.x;
    __shared__ float slot[4];
    __shared__ __align__(16) _Float16 sb[17408];

    float mt = -INFINITY;
    for (int s = 0; s < 64; ++s) mt = fmaxf(mt, trans[tid + s * 256]);
    #pragma unroll
    for (int o = 32; o; o >>= 1) mt = fmaxf(mt, __shfl_xor(mt, o));
    if ((tid & 63) == 0) slot[tid >> 6] = mt;
    __syncthreads();
    const float mT = fmaxf(fmaxf(slot[0], slot[1]), fmaxf(slot[2], slot[3]));

    // EtA = E^T in A-layout: A[m][k] = E[k][m] = exp(trans[k*128+m]-mT)
    for (int s = 0; s < 64; ++s) {
        int e = tid + s * 256;
        int k = e >> 7, m = e & 127;
        float v = __expf(trans[e] - mT);
        sb[((((m >> 4) * 4 + (k >> 5)) * 4 + ((k >> 3) & 3)) * 16 + (m & 15)) * 8 + (k & 7)] =
            (_Float16)v;
    }
    __syncthreads();
    for (int s = 0; s < 8; ++s) {
        int x = (tid + s * 256) * 8;
        *(half8*)&EtA[x] = *(const half8*)&sb[x];
    }
    __syncthreads();

    // EtB: element (k=j, n=i) = E[i][j], padded B-layout
    for (int s = 0; s < 64; ++s) {
        int e = tid + s * 256;
        int i = e >> 7, j = e & 127;
        float v = __expf(trans[e] - mT);
        sb[((i >> 4) * 16 + (j >> 3)) * 136 + (i & 15) * 8 + (j & 7)] = (_Float16)v;
    }
    __syncthreads();
    for (int s = 0; s < 9; ++s) {
        int g = tid + s * 256;
        if (g < 2176) {
            int x = g * 8;
            *(half8*)&EtB[x] = *(const half8*)&sb[x];
        }
    }
    if (tid == 0) mTout[0] = mT;
}

// ================= phase 1: chunk products, zero in-loop VMEM =================
__global__ __launch_bounds__(256, 2) void crf_chunkmat3(
    const float* __restrict__ em,
    const _Float16* __restrict__ EtA, const _Float16* __restrict__ EtB,
    const float* __restrict__ mTws,
    _Float16* __restrict__ Pst, float* __restrict__ Sout)
{
    const int c = blockIdx.x;     // 0..NMAT-1
    const int b = blockIdx.y;
    const int tid = threadIdx.x;
    const int w = tid >> 6, lane = tid & 63;
    const int quad = lane >> 4, lm = lane & 15;

    __shared__ __align__(16) _Float16 buf[17408];   // 34.8 KB padded B-layout
    __shared__ __align__(16) float gAll[16 * KDIM]; // em chunk, then g in-place (8 KB)
    __shared__ float mE[16];
    __shared__ float slotV[4];

    const float mT = mTws[0];
    const int t0 = c * CH_L + 1;
    const float* emb = em + (size_t)b * TLEN * KDIM;

    // --- A fragments (E^T), loop-invariant: 8 x half8 = 32 VGPRs ---
    half8 EA[2][4];
    #pragma unroll
    for (int r = 0; r < 2; ++r) {
        const int tr = 2 * w + r;
        #pragma unroll
        for (int kt = 0; kt < 4; ++kt)
            EA[r][kt] = *(const half8*)&EtA[(((tr * 4 + kt) * 4 + quad) * 16 + lm) * 8];
    }

    // --- stage all 16 em rows for this chunk (em[t0 .. t0+15]) ---
    #pragma unroll
    for (int s = 0; s < 2; ++s) {
        int i4 = tid + s * 256;           // 512 float4s
        *(float4*)&gAll[i4 * 4] = *(const float4*)&emb[t0 * KDIM + i4 * 4];
    }
    __syncthreads();

    // --- per-row maxes: wave w handles rows w*4 .. w*4+3 ---
    #pragma unroll
    for (int r2 = 0; r2 < 4; ++r2) {
        const int r = w * 4 + r2;
        float v = fmaxf(gAll[r * KDIM + lane], gAll[r * KDIM + 64 + lane]);
        #pragma unroll
        for (int o = 32; o; o >>= 1) v = fmaxf(v, __shfl_xor(v, o));
        if (lane == 0) mE[r] = v;
    }
    __syncthreads();

    // --- g in place: gAll[r][j] = exp(em - mE[r]) ---
    #pragma unroll
    for (int s = 0; s < 8; ++s) {
        int idx = tid + s * 256;
        gAll[idx] = __expf(gAll[idx] - mE[idx >> 7]);
    }
    __syncthreads();

    // --- init buf = M_t0^T = diag(g0)*E^T ---
    for (int s = 0; s < 8; ++s) {
        int g = tid + s * 256;                    // 2048 data groups
        int row = g >> 4, nl = g & 15;
        int addr = row * 136 + nl * 8;
        int j0 = (row & 15) * 8;
        half8 e = *(const half8*)&EtB[addr];
        const float* g0p = &gAll[j0];
        half8 o;
        #pragma unroll
        for (int x = 0; x < 8; ++x) o[x] = (_Float16)((float)e[x] * g0p[x]);
        *(half8*)&buf[addr] = o;
    }
    float S = mT;
    if (tid == 0) {
        #pragma unroll
        for (int r = 0; r < 16; ++r) S += mE[r];
    }
    __syncthreads();

    floatx4 acc[2][8];

    for (int it = 1; it < 16; ++it) {
        #pragma unroll
        for (int r = 0; r < 2; ++r)
            #pragma unroll
            for (int nt = 0; nt < 8; ++nt)
                acc[r][nt] = (floatx4){0.f, 0.f, 0.f, 0.f};

        // ---- C = E^T * Pt : A regs, B from LDS ----
        #pragma unroll
        for (int kt = 0; kt < 4; ++kt) {
            #pragma unroll
            for (int nt = 0; nt < 8; ++nt) {
                half8 bb = *(const half8*)&buf[(nt * 16 + kt * 4 + quad) * 136 + lm * 8];
                acc[0][nt] = __builtin_amdgcn_mfma_f32_16x16x32_f16(EA[0][kt], bb, acc[0][nt], 0, 0, 0);
                acc[1][nt] = __builtin_amdgcn_mfma_f32_16x16x32_f16(EA[1][kt], bb, acc[1][nt], 0, 0, 0);
            }
        }

        // row-scale factors g[j], j = tr*16 + quad*4 + q
        const float* gc = &gAll[it * KDIM];
        const float4 gr0 = *(const float4*)&gc[(2 * w + 0) * 16 + quad * 4];
        const float4 gr1 = *(const float4*)&gc[(2 * w + 1) * 16 + quad * 4];

        float lmax = 0.f;
        #pragma unroll
        for (int nt = 0; nt < 8; ++nt) {
            floatx4 v0 = acc[0][nt], v1 = acc[1][nt];
            float a0 = fmaxf(fmaxf(v0.x * gr0.x, v0.y * gr0.y), fmaxf(v0.z * gr0.z, v0.w * gr0.w));
            float a1 = fmaxf(fmaxf(v1.x * gr1.x, v1.y * gr1.y), fmaxf(v1.z * gr1.z, v1.w * gr1.w));
            lmax = fmaxf(lmax, fmaxf(a0, a1));
        }
        #pragma unroll
        for (int o = 32; o; o >>= 1) lmax = fmaxf(lmax, __shfl_xor(lmax, o));
        if (lane == 0) slotV[w] = lmax;
        __syncthreads();                                   // barrier 1 (lgkm only)

        const float rr = fmaxf(fmaxf(slotV[0], slotV[1]), fmaxf(slotV[2], slotV[3]));
        const float rinv = 1.0f / rr;
        if (tid == 0) S += mT + __logf(rr);

        // ---- write normalized diag(g)*C back to B-layout: 16x ds_write_b64 ----
        const float4 s0 = {gr0.x * rinv, gr0.y * rinv, gr0.z * rinv, gr0.w * rinv};
        const float4 s1 = {gr1.x * rinv, gr1.y * rinv, gr1.z * rinv, gr1.w * rinv};
        const int jlb = (quad & 1) * 4;
        #pragma unroll
        for (int r = 0; r < 2; ++r) {
            const int tr = 2 * w + r;
            const int kh = tr * 2 + (quad >> 1);
            const float4 sc = r ? s1 : s0;
            #pragma unroll
            for (int nt = 0; nt < 8; ++nt) {
                const floatx4 v = acc[r][nt];
                half4 o;
                o[0] = (_Float16)(v.x * sc.x);
                o[1] = (_Float16)(v.y * sc.y);
                o[2] = (_Float16)(v.z * sc.z);
                o[3] = (_Float16)(v.w * sc.w);
                *(half4*)&buf[(nt * 16 + kh) * 136 + lm * 8 + jlb] = o;
            }
        }
        __syncthreads();                                   // barrier 2 (lgkm only)
    }

    // --- store chunk in scan layout: unit u = K*128+j holds P[K*8+e][j] ---
    _Float16* Pc = Pst + ((size_t)(b * NMAT + c)) * 16384;
    for (int s = 0; s < 8; ++s) {
        int u = tid + s * 256;                  // 0..2047
        int K = u >> 7, j = u & 127;
        const int base = ((K >> 1) * 16 + (j >> 3)) * 136 + (j & 7);
        const int eoff = (K & 1) * 64;          // ((K&1)*8)*8
        half8 v;
        #pragma unroll
        for (int e = 0; e < 8; ++e) v[e] = buf[base + eoff + e * 8];
        *(half8*)&Pc[u * 8] = v;
    }
    if (tid == 0) Sout[b * NMAT + c] = S;
}

// ================= phase 2: scan v3 — LDS-dbuf chunks, serial-k matvec =========
// State: p (f32, lag-normalized) + scalar L with invariant
//   alpha_enter(c)[j] = L + log p[j].
// Step: q_j = sum_k p_k P[k][j]; aEnter[c+1] = L + S_c + log q_j;
//   sigma = previous step's q[0]; p' = q/sigma; L += S_c + log sigma.
__global__ __launch_bounds__(512, 2) void crf_scan3(
    const float* __restrict__ em, const _Float16* __restrict__ Pst,
    const float* __restrict__ S, float* __restrict__ aEnter)
{
    const int b = blockIdx.x;
    const int tid = threadIdx.x;
    const int j = tid & 127, h = tid >> 7;
    const int lane = tid & 63, wv = tid >> 6;

    __shared__ __align__(16) _Float16 Pbuf[2][16384];  // 64 KB double buffer
    __shared__ __align__(16) float p_lds[2][KDIM];
    __shared__ __align__(16) float part[KDIM][4];
    __shared__ float islot[2];
    __shared__ float qpub[2];

    float* aeb = aEnter + (size_t)b * NCH * KDIM;
    const _Float16* Pb = Pst + (size_t)b * NMAT * 16384;

    // stage chunk 0
    {
        const uint4* G0 = (const uint4*)Pb;
        uint4* B0 = (uint4*)&Pbuf[0][0];
        #pragma unroll
        for (int s2 = 0; s2 < 4; ++s2) {
            int u = tid + s2 * 512;
            B0[u] = G0[u];
        }
    }

    // init p from em[b,0,:]
    float a0 = 0.f;
    if (tid < KDIM) a0 = em[(size_t)b * TLEN * KDIM + tid];
    {
        float v = (tid < KDIM) ? a0 : -INFINITY;
        #pragma unroll
        for (int o = 32; o; o >>= 1) v = fmaxf(v, __shfl_xor(v, o));
        if (lane == 0 && wv < 2) islot[wv] = v;
    }
    if (tid == 0) qpub[1] = 1.0f;     // sigma for step 0
    __syncthreads();
    float L = fmaxf(islot[0], islot[1]);
    if (tid < KDIM) {
        aeb[tid] = a0;
        p_lds[0][tid] = __expf(a0 - L);
    }
    __syncthreads();

    for (int c = 0; c < NMAT; ++c) {
        const int cb = c & 1, nb = cb ^ 1;

        // prefetch chunk c+1 into regs (off critical path until LDS store)
        uint4 pre[4];
        {
            const int cn = (c + 1 < NMAT) ? (c + 1) : c;
            const uint4* Gn = (const uint4*)(Pb + (size_t)cn * 16384);
            #pragma unroll
            for (int s2 = 0; s2 < 4; ++s2) pre[s2] = Gn[tid + s2 * 512];
        }
        const float s_c = S[b * NMAT + c];

        // matvec partial: k in [h*32, h*32+32)
        float acc0 = 0.f, acc1 = 0.f, acc2 = 0.f, acc3 = 0.f;
        #pragma unroll
        for (int s = 0; s < 4; ++s) {
            const int K = h * 4 + s;
            const half8 P8 = *(const half8*)&Pbuf[cb][(K * 128 + j) * 8];
            const float4 pa = *(const float4*)&p_lds[cb][K * 8];
            const float4 pb2 = *(const float4*)&p_lds[cb][K * 8 + 4];
            float t = 0.f;
            t = fmaf(pa.x, (float)P8[0], t);
            t = fmaf(pa.y, (float)P8[1], t);
            t = fmaf(pa.z, (float)P8[2], t);
            t = fmaf(pa.w, (float)P8[3], t);
            t = fmaf(pb2.x, (float)P8[4], t);
            t = fmaf(pb2.y, (float)P8[5], t);
            t = fmaf(pb2.z, (float)P8[6], t);
            t = fmaf(pb2.w, (float)P8[7], t);
            if (s == 0) acc0 = t; else if (s == 1) acc1 = t;
            else if (s == 2) acc2 = t; else acc3 = t;
        }
        part[j][h] = (acc0 + acc1) + (acc2 + acc3);

        // store prefetched chunk into the other buffer
        {
            uint4* BN = (uint4*)&Pbuf[nb][0];
            #pragma unroll
            for (int s2 = 0; s2 < 4; ++s2) BN[tid + s2 * 512] = pre[s2];
        }
        __syncthreads();                       // barrier A

        if (h == 0) {
            const float4 pj = *(const float4*)&part[j][0];
            const float q = (pj.x + pj.y) + (pj.z + pj.w);
            aeb[(c + 1) * KDIM + j] = L + s_c + __logf(q);
            const float sigma = qpub[nb];      // previous step's publish
            if (j == 0) qpub[cb] = q;          // publish for next step
            p_lds[nb][j] = q / sigma;
            L += s_c + __logf(sigma);
        }
        __syncthreads();                       // barrier B
    }
}

// ================= phase 3: fp32 replay within chunks + logZ (R4, proven) =======
__global__ __launch_bounds__(256, 2) void crf_replay(
    const float* __restrict__ trans, const float* __restrict__ em,
    const int* __restrict__ seq_lens, const float* __restrict__ aEnter,
    float* __restrict__ alpha, float* __restrict__ logZ)
{
    const int c = blockIdx.x, b = blockIdx.y;
    const int tid = threadIdx.x;
    const int j = tid & 127, h = tid >> 7;

    __shared__ __align__(16) float p_lds[2][KDIM];
    __shared__ float part[2][KDIM];
    __shared__ float mslot[2][2];
    __shared__ float red[2];

    float Ereg[64];
    #pragma unroll
    for (int k = 0; k < 64; ++k) Ereg[k] = __expf(trans[(h * 64 + k) * KDIM + j]);

    const int len = seq_lens[b];
    const float* emb = em + (size_t)b * TLEN * KDIM;
    float* outb = alpha + (size_t)b * TLEN * KDIM;

    float a = 0.f, last_a = 0.f;
    if (h == 0) a = aEnter[((size_t)b * NCH + c) * KDIM + j];
    if (c == 0 && h == 0) {
        outb[j] = a;
        if (len == 1) last_a = a;
    }
    {
        float v = (h == 0) ? a : -INFINITY;
        #pragma unroll
        for (int o = 32; o; o >>= 1) v = fmaxf(v, __shfl_xor(v, o));
        if ((tid & 63) == 0 && h == 0) mslot[0][tid >> 6] = v;
    }
    __syncthreads();
    float m = fmaxf(mslot[0][0], mslot[0][1]);

    const int t_begin = c * CH_L + 1;
    const int t_end = (c == NCH - 1) ? (TLEN - 1) : (c * CH_L + CH_L);

    for (int t = t_begin; t <= t_end; ++t) {
        const int par = t & 1;
        float em_t = 0.f;
        if (h == 0) {
            em_t = emb[t * KDIM + j];
            p_lds[par][j] = __expf(a - m);
            float v = a;
            #pragma unroll
            for (int o = 32; o; o >>= 1) v = fmaxf(v, __shfl_xor(v, o));
            if ((tid & 63) == 0) mslot[par][tid >> 6] = v;
        }
        __syncthreads();
        float acc0 = 0.f, acc1 = 0.f, acc2 = 0.f, acc3 = 0.f;
        const float4* p4 = (const float4*)&p_lds[par][h * 64];
        #pragma unroll
        for (int k4 = 0; k4 < 16; ++k4) {
            float4 pv = p4[k4];
            acc0 = fmaf(pv.x, Ereg[4 * k4 + 0], acc0);
            acc1 = fmaf(pv.y, Ereg[4 * k4 + 1], acc1);
            acc2 = fmaf(pv.z, Ereg[4 * k4 + 2], acc2);
            acc3 = fmaf(pv.w, Ereg[4 * k4 + 3], acc3);
        }
        if (h) part[par][j] = (acc0 + acc1) + (acc2 + acc3);
        __syncthreads();
        if (h == 0) {
            const float q = ((acc0 + acc1) + (acc2 + acc3)) + part[par][j];
            a = em_t + m + __logf(q);
            outb[t * KDIM + j] = a;
            if (t == len - 1) last_a = a;
            m = fmaxf(mslot[par][0], mslot[par][1]);
        }
    }

    const bool blockowns = (len == 1) ? (c == 0) : (((len - 2) >> 4) == c);
    __syncthreads();
    if (blockowns) {
        float v = (h == 0) ? last_a : -INFINITY;
        #pragma unroll
        for (int o = 32; o; o >>= 1) v = fmaxf(v, __shfl_xor(v, o));
        if ((tid & 63) == 0 && h == 0) mslot[0][tid >> 6] = v;
        __syncthreads();
        const float m2 = fmaxf(mslot[0][0], mslot[0][1]);
        float e = (h == 0) ? __expf(last_a - m2) : 0.f;
        #pragma unroll
        for (int o = 32; o; o >>= 1) e += __shfl_xor(e, o);
        if ((tid & 63) == 0 && h == 0) red[tid >> 6] = e;
        __syncthreads();
        if (tid == 0) logZ[b] = m2 + __logf(red[0] + red[1]);
    }
}

// ================= fallback (proven R1 kernel) for small ws =================
__global__ __launch_bounds__(256) void crf_forward_fallback(
    const float* __restrict__ trans, const float* __restrict__ em,
    const int* __restrict__ seq_lens, float* __restrict__ alpha_out,
    float* __restrict__ logZ_out)
{
    const int b = blockIdx.x;
    const int tid = threadIdx.x;
    const int j = tid & (KDIM - 1);
    const int h = tid >> 7;

    __shared__ __align__(16) float p_lds[KDIM];
    __shared__ float part[KDIM];
    __shared__ float red[8];

    float Ereg[64];
    #pragma unroll
    for (int k = 0; k < 64; ++k) Ereg[k] = __expf(trans[(h * 64 + k) * KDIM + j]);

    const int len = seq_lens[b];
    const float* emb = em + (size_t)b * TLEN * KDIM;
    float* outb = alpha_out + (size_t)b * TLEN * KDIM;

    float a = 0.f, last_a = 0.f;
    if (h == 0) {
        a = emb[j];
        outb[j] = a;
        if (len == 1) last_a = a;
    }
    for (int t = 1; t < TLEN; ++t) {
        {
            float v = (h == 0) ? a : -INFINITY;
            #pragma unroll
            for (int o = 32; o >= 1; o >>= 1) v = fmaxf(v, __shfl_xor(v, o));
            if ((tid & 63) == 0) red[tid >> 6] = v;
        }
        __syncthreads();
        const float m = fmaxf(red[0], red[1]);
        if (h == 0) p_lds[j] = __expf(a - m);
        __syncthreads();
        float em_t = 0.f;
        if (h == 0) em_t = emb[t * KDIM + j];
        float acc0 = 0.f, acc1 = 0.f, acc2 = 0.f, acc3 = 0.f;
        const float4* p4 = (const float4*)(p_lds + h * 64);
        #pragma unroll
        for (int k4 = 0; k4 < 16; ++k4) {
            float4 pv = p4[k4];
            acc0 = fmaf(pv.x, Ereg[4 * k4 + 0], acc0);
            acc1 = fmaf(pv.y, Ereg[4 * k4 + 1], acc1);
            acc2 = fmaf(pv.z, Ereg[4 * k4 + 2], acc2);
            acc3 = fmaf(pv.w, Ereg[4 * k4 + 3], acc3);
        }
        const float acc = (acc0 + acc1) + (acc2 + acc3);
        if (h == 1) part[j] = acc;
        __syncthreads();
        if (h == 0) {
            const float q = acc + part[j];
            a = em_t + m + __logf(q);
            outb[t * KDIM + j] = a;
            if (t == len - 1) last_a = a;
        }
    }
    {
        float v = (h == 0) ? last_a : -INFINITY;
        #pragma unroll
        for (int o = 32; o >= 1; o >>= 1) v = fmaxf(v, __shfl_xor(v, o));
        if ((tid & 63) == 0) red[tid >> 6] = v;
    }
    __syncthreads();
    const float m2 = fmaxf(red[0], red[1]);
    float e = (h == 0) ? __expf(last_a - m2) : 0.f;
    #pragma unroll
    for (int o = 32; o >= 1; o >>= 1) e += __shfl_xor(e, o);
    if ((tid & 63) == 0) red[4 + (tid >> 6)] = e;
    __syncthreads();
    if (tid == 0) logZ_out[b] = m2 + logf(red[4] + red[5]);
}

extern "C" void kernel_launch(void* const* d_in, const int* in_sizes, int n_in,
                              void* d_out, int out_size, void* d_ws, size_t ws_size,
                              hipStream_t stream) {
    const float* trans    = (const float*)d_in[0];   // K*K
    const float* em       = (const float*)d_in[1];   // B*T*K
    const int*   seq_lens = (const int*)d_in[2];     // B

    float* alpha_out = (float*)d_out;                            // B*T*K
    float* logZ_out  = alpha_out + (size_t)BATCH * TLEN * KDIM;  // B

    if (ws_size < (size_t)WS_NEED) {
        crf_forward_fallback<<<BATCH, 256, 0, stream>>>(trans, em, seq_lens,
                                                        alpha_out, logZ_out);
        return;
    }

    char* ws = (char*)d_ws;
    _Float16* Pst  = (_Float16*)(ws + WS_PST);
    _Float16* EtA  = (_Float16*)(ws + WS_ETA);
    _Float16* EtB  = (_Float16*)(ws + WS_ETB);
    float*    Slog = (float*)(ws + WS_SLOG);
    float*    aEnt = (float*)(ws + WS_AENT);
    float*    mTws = (float*)(ws + WS_MT);

    crf_prep2<<<1, 256, 0, stream>>>(trans, EtA, EtB, mTws);
    crf_chunkmat3<<<dim3(NMAT, BATCH), 256, 0, stream>>>(em, EtA, EtB, mTws, Pst, Slog);
    crf_scan3<<<BATCH, 512, 0, stream>>>(em, Pst, Slog, aEnt);
    crf_replay<<<dim3(NCH, BATCH), 256, 0, stream>>>(trans, em, seq_lens, aEnt,
                                                     alpha_out, logZ_out);
}